// Round 4
// baseline (546.502 us; speedup 1.0000x reference)
//
#include <hip/hip_runtime.h>
#include <math.h>

#define NN 102400
#define FD 128
#define KC 16
#define BG 64
#define NPG 1600
#define NE 3276800

__device__ __forceinline__ void glob_addf(float* p, float v) {
  unsafeAtomicAdd(p, v);
}
__device__ __forceinline__ unsigned f2bf(float f) {
  unsigned u = __float_as_uint(f);
  u += 0x7FFFu + ((u >> 16) & 1u);
  return (u >> 16) & 0xFFFFu;
}
__device__ __forceinline__ float bf2f(unsigned h) {
  return __uint_as_float(h << 16);
}

// -------------------- s = softmax(softmax(x@W+b)) + src histogram --------------------
__global__ __launch_bounds__(256) void k_s(const float* __restrict__ x,
    const float* __restrict__ W, const float* __restrict__ bb,
    const int* __restrict__ esrc, float* __restrict__ s,
    unsigned* __restrict__ nodecnt) {
  const int t = threadIdx.x;
  const int n = blockIdx.x * 256 + t;
  float acc[KC];
#pragma unroll
  for (int k = 0; k < KC; ++k) acc[k] = bb[k];
  const float4* xr = (const float4*)(x + (size_t)n * FD);
#pragma unroll 4
  for (int c = 0; c < FD / 4; ++c) {
    float4 v = xr[c];
    const float* wr = W + c * 4 * KC;
#pragma unroll
    for (int k = 0; k < KC; ++k)
      acc[k] += v.x * wr[k] + v.y * wr[KC + k] + v.z * wr[2 * KC + k] + v.w * wr[3 * KC + k];
  }
#pragma unroll
  for (int r = 0; r < 2; ++r) {
    float m = acc[0];
#pragma unroll
    for (int k = 1; k < KC; ++k) m = fmaxf(m, acc[k]);
    float sum = 0.f;
#pragma unroll
    for (int k = 0; k < KC; ++k) { acc[k] = expf(acc[k] - m); sum += acc[k]; }
    float inv = 1.f / sum;
#pragma unroll
    for (int k = 0; k < KC; ++k) acc[k] *= inv;
  }
  float4* so = (float4*)(s + (size_t)n * KC);
  so[0] = make_float4(acc[0], acc[1], acc[2], acc[3]);
  so[1] = make_float4(acc[4], acc[5], acc[6], acc[7]);
  so[2] = make_float4(acc[8], acc[9], acc[10], acc[11]);
  so[3] = make_float4(acc[12], acc[13], acc[14], acc[15]);
  // src histogram: fire-and-forget global atomics (no return -> no stall)
  for (int e = n; e < NE; e += NN) atomicAdd(&nodecnt[esrc[e]], 1u);
}

// -------------------- scan stage A: 100 blocks x 1024 counters --------------------
__global__ __launch_bounds__(1024) void k_scanA(const unsigned* __restrict__ cnt,
    unsigned* __restrict__ scanned, unsigned* __restrict__ cur,
    unsigned* __restrict__ bsum) {
  __shared__ unsigned wsum[16];
  const int t = threadIdx.x, b = blockIdx.x;
  const int lane = t & 63;
  unsigned v = cnt[b * 1024 + t];
  unsigned inc = v;
#pragma unroll
  for (int o = 1; o < 64; o <<= 1) {
    unsigned nb = __shfl_up(inc, o, 64);
    if (lane >= o) inc += nb;
  }
  if (lane == 63) wsum[t >> 6] = inc;
  __syncthreads();
  if (t == 0) {
    unsigned run = 0;
#pragma unroll
    for (int i = 0; i < 16; ++i) { unsigned c = wsum[i]; wsum[i] = run; run += c; }
    bsum[b] = run;
  }
  __syncthreads();
  unsigned excl = inc - v + wsum[t >> 6];
  scanned[b * 1024 + t] = excl;
  cur[b * 1024 + t] = excl;
}

// -------------------- scan stage B: block bases --------------------
__global__ void k_scanB(const unsigned* __restrict__ bsum,
    unsigned* __restrict__ base, unsigned* __restrict__ scanned) {
  if (threadIdx.x == 0) {
    unsigned run = 0;
    for (int i = 0; i < 100; ++i) { base[i] = run; run += bsum[i]; }
    base[100] = run;          // == NE
    scanned[NN] = 0;          // sentinel: row end of last node
  }
}

// -------------------- scatter edges into CSR order (payload: dst_local<<16 | bf16 w) ----
__global__ __launch_bounds__(256) void k_scatter(const float* __restrict__ ew,
    const int* __restrict__ esrc, const int* __restrict__ edst,
    unsigned* __restrict__ cur, const unsigned* __restrict__ base,
    unsigned* __restrict__ spk) {
  const int tid = blockIdx.x * 256 + threadIdx.x;
  for (int e = tid; e < NE; e += 2048 * 256) {
    int s0 = esrc[e];
    int d0 = edst[e];
    float w = ew[e];
    unsigned r = atomicAdd(&cur[s0], 1u);
    unsigned pos = r + base[(unsigned)s0 >> 10];
    unsigned g = (unsigned)s0 / (unsigned)NPG;
    unsigned dl = (unsigned)d0 - g * NPG;
    spk[pos] = (dl << 16) | f2bf(w);
  }
}

// -------------------- adj = S^T A S via CSR register segment-sum; den folded ----------
__global__ __launch_bounds__(256, 8) void k_adj(const float* __restrict__ s,
    const unsigned* __restrict__ spk, const unsigned* __restrict__ scanned,
    const unsigned* __restrict__ base, float* __restrict__ adj_raw,
    float* __restrict__ den) {
  __shared__ float red[16 * 256];   // 16 slices x 16x16 cells
  __shared__ float scr[4];
  const int t = threadIdx.x;
  const int g = blockIdx.x & 63;          // XCD-spread graphs
  const int oct = blockIdx.x >> 6;        // 0..31
  const int l = t & 15;
  const int slice = oct * 16 + (t >> 4);  // 0..511 per graph
  const int sw = (t >> 4) & 3;            // slice-in-wave
  const float* sG = s + (size_t)g * NPG * KC;
  float acc[16];
#pragma unroll
  for (int k = 0; k < 16; ++k) acc[k] = 0.f;
  float dacc = 0.f;
  for (int i = slice; i < NPG; i += 512) {
    const int n = g * NPG + i;
    unsigned rp0 = scanned[n] + base[(unsigned)n >> 10];
    unsigned rp1 = scanned[n + 1] + base[(unsigned)(n + 1) >> 10];
    float m = 0.f;
    unsigned e = rp0;
    for (; e + 2 <= rp1; e += 2) {
      unsigned pk0 = spk[e], pk1 = spk[e + 1];
      float sv0 = sG[(pk0 >> 16) * KC + l];
      float sv1 = sG[(pk1 >> 16) * KC + l];
      float w0 = bf2f(pk0 & 0xFFFFu), w1 = bf2f(pk1 & 0xFFFFu);
      float t0 = w0 * sv0, t1 = w1 * sv1;
      m += t0 + t1;
      dacc = fmaf(t0, sv0, dacc);
      dacc = fmaf(t1, sv1, dacc);
    }
    if (e < rp1) {
      unsigned pk0 = spk[e];
      float sv0 = sG[(pk0 >> 16) * KC + l];
      float t0 = bf2f(pk0 & 0xFFFFu) * sv0;
      m += t0;
      dacc = fmaf(t0, sv0, dacc);
    }
    const float si = sG[i * KC + l];
#pragma unroll
    for (int k = 0; k < 16; ++k) {
      float sk = __shfl(si, sw * 16 + k, 64);
      acc[k] = fmaf(sk, m, acc[k]);
    }
  }
  const int sb = t >> 4;
#pragma unroll
  for (int k = 0; k < 16; ++k) red[sb * 256 + k * 16 + l] = acc[k];
  __syncthreads();
  float sum = 0.f;
#pragma unroll
  for (int sl = 0; sl < 16; ++sl) sum += red[sl * 256 + t];
  glob_addf(adj_raw + g * 256 + t, sum);
#pragma unroll
  for (int o = 32; o > 0; o >>= 1) dacc += __shfl_down(dacc, o, 64);
  __syncthreads();
  if ((t & 63) == 0) scr[t >> 6] = dacc;
  __syncthreads();
  if (t == 0) glob_addf(den, scr[0] + scr[1] + scr[2] + scr[3]);
}

// -------------------- node pass: CC = S^T S, out_x = S^T X --------------------
__global__ __launch_bounds__(256, 8) void k_mid(const float* __restrict__ s,
    const float* __restrict__ x, float* __restrict__ cc_raw,
    float* __restrict__ outx_raw) {
  __shared__ float st[100 * KC];
  const int t = threadIdx.x;
  const int g = blockIdx.x >> 4, sub = blockIdx.x & 15;
  const int n0 = g * NPG + sub * 100;
  const int j = t & 127, h = t >> 7;
  const int kc = t >> 4, lc = t & 15;
  for (int u = t; u < 100 * KC; u += 256) st[u] = s[(size_t)n0 * KC + u];
  __syncthreads();
  float accX[8] = {0.f, 0.f, 0.f, 0.f, 0.f, 0.f, 0.f, 0.f};
  float accC = 0.f;
  for (int i = 0; i < 100; ++i) {
    const float xv = x[(size_t)(n0 + i) * FD + j];
    const float* si = st + i * KC;
#pragma unroll
    for (int kk = 0; kk < 8; ++kk) accX[kk] = fmaf(si[h * 8 + kk], xv, accX[kk]);
    accC = fmaf(si[kc], si[lc], accC);
  }
#pragma unroll
  for (int kk = 0; kk < 8; ++kk)
    glob_addf(outx_raw + g * 2048 + (h * 8 + kk) * 128 + j, accX[kk]);
  glob_addf(cc_raw + g * 256 + t, accC);
}

// -------------------- finalize: adj normalize, trace, ortho, SELU --------------------
__device__ __forceinline__ float bred(float v, float* scr) {
#pragma unroll
  for (int o = 32; o > 0; o >>= 1) v += __shfl_down(v, o, 64);
  __syncthreads();
  if ((threadIdx.x & 63) == 0) scr[threadIdx.x >> 6] = v;
  __syncthreads();
  return scr[0] + scr[1] + scr[2] + scr[3];
}

__global__ __launch_bounds__(256) void k_post(const float* __restrict__ adj_raw,
    const float* __restrict__ cc_raw, const float* __restrict__ outx_raw,
    float* __restrict__ out, float* __restrict__ ws_num, float* __restrict__ ws_ortho) {
  const int b = blockIdx.x, t = threadIdx.x;
  const int k = t >> 4, l = t & 15;
  __shared__ float m[16 * 17];
  __shared__ float dk[16];
  __shared__ float scr[4];
  const float raw = adj_raw[b * 256 + t];
  const float masked = (k == l) ? 0.f : raw;
  m[k * 17 + l] = masked;
  __syncthreads();
  if (t < 16) {
    float rs = 0.f;
#pragma unroll
    for (int ll = 0; ll < 16; ++ll) rs += m[t * 17 + ll];
    dk[t] = sqrtf(rs) + 1e-12f;
  }
  __syncthreads();
  out[131072 + b * 256 + t] = masked / (dk[k] * dk[l]);
  float tr = bred((k == l) ? raw : 0.f, scr);
  if (t == 0) glob_addf(ws_num, tr);
  const float c = cc_raw[b * 256 + t];
  float n2 = bred(c * c, scr);
  float diff = c / sqrtf(n2) - ((k == l) ? 0.25f : 0.f);
  float d2 = bred(diff * diff, scr);
  if (t == 0) glob_addf(ws_ortho, sqrtf(d2));
  for (int idx = b * 256 + t; idx < 131072; idx += 16384) {
    float xv = outx_raw[idx];
    out[idx] = xv > 0.f ? 1.0507009873554805f * xv
                        : 1.0507009873554805f * 1.6732632423543772f * expm1f(xv);
  }
}

__global__ void k_last(const float* __restrict__ scal, float* __restrict__ out) {
  out[147456] = -scal[1] / scal[0];      // -num/den
  out[147457] = scal[2] * (1.f / 64.f);  // mean ortho
}

// -------------------- launch --------------------
extern "C" void kernel_launch(void* const* d_in, const int* in_sizes, int n_in,
                              void* d_out, int out_size, void* d_ws, size_t ws_size,
                              hipStream_t stream) {
  const float* x  = (const float*)d_in[0];
  const float* W  = (const float*)d_in[1];
  const float* bb = (const float*)d_in[2];
  const float* ew = (const float*)d_in[3];
  const int* esrc = (const int*)d_in[4];
  const int* edst = (const int*)d_in[5];
  float* out = (float*)d_out;
  float* ws = (float*)d_ws;

  float* s_buf   = ws;                                   // 1,638,400 f
  float* adj_raw = s_buf + (size_t)NN * KC;              // 16,384 f
  float* cc_raw  = adj_raw + 16384;                      // 16,384 f
  float* outx    = cc_raw + 16384;                       // 131,072 f
  float* scal    = outx + 131072;                        // 8 f: [0]=den [1]=num [2]=ortho
  unsigned* nodecnt = (unsigned*)(scal + 8);             // 102,400 u (memset with above)
  unsigned* scanned = nodecnt + NN;                      // 102,404 u (NN+1 used)
  unsigned* cur     = scanned + NN + 4;                  // 102,400 u
  unsigned* bsum    = cur + NN;                          // 128 u
  unsigned* base    = bsum + 128;                        // 104 u (101 used)
  unsigned* spk     = base + 104;                        // NE u
  // total ~= 21.9 MB (< 33.69 MB proven available)

  hipMemsetAsync(adj_raw, 0,
      (size_t)(16384 + 16384 + 131072 + 8 + NN) * sizeof(float), stream);
  k_s<<<NN / 256, 256, 0, stream>>>(x, W, bb, esrc, s_buf, nodecnt);
  k_scanA<<<100, 1024, 0, stream>>>(nodecnt, scanned, cur, bsum);
  k_scanB<<<1, 64, 0, stream>>>(bsum, base, scanned);
  k_scatter<<<2048, 256, 0, stream>>>(ew, esrc, edst, cur, base, spk);
  k_adj<<<BG * 32, 256, 0, stream>>>(s_buf, spk, scanned, base, adj_raw, scal);
  k_mid<<<BG * 16, 256, 0, stream>>>(s_buf, x, cc_raw, outx);
  k_post<<<64, 256, 0, stream>>>(adj_raw, cc_raw, outx, out, scal + 1, scal + 2);
  k_last<<<1, 1, 0, stream>>>(scal, out);
}

// Round 5
// 329.028 us; speedup vs baseline: 1.6610x; 1.6610x over previous
//
#include <hip/hip_runtime.h>
#include <math.h>

#define NN 102400
#define FD 128
#define KC 16
#define BG 64
#define NPG 1600
#define NE 3276800
#define HB 1024          // level-1 hist/scatter blocks
#define EH (NE / HB)     // 3200 edges per block
#define SMAX 56          // ceil(max edges-per-graph / 1024); 56*1024=57344 >> 51200+25sigma

__device__ __forceinline__ void glob_addf(float* p, float v) {
  unsafeAtomicAdd(p, v);
}
__device__ __forceinline__ unsigned f2bf(float f) {
  unsigned u = __float_as_uint(f);
  u += 0x7FFFu + ((u >> 16) & 1u);
  return (u >> 16) & 0xFFFFu;
}
__device__ __forceinline__ float bf2f(unsigned h) {
  return __uint_as_float(h << 16);
}

// -------------------- s = softmax(softmax(x@W+b)) --------------------
__global__ __launch_bounds__(256) void k_s(const float* __restrict__ x,
    const float* __restrict__ W, const float* __restrict__ bb,
    float* __restrict__ s) {
  const int t = threadIdx.x;
  const int n = blockIdx.x * 256 + t;
  float acc[KC];
#pragma unroll
  for (int k = 0; k < KC; ++k) acc[k] = bb[k];
  const float4* xr = (const float4*)(x + (size_t)n * FD);
#pragma unroll 4
  for (int c = 0; c < FD / 4; ++c) {
    float4 v = xr[c];
    const float* wr = W + c * 4 * KC;   // wave-uniform -> scalar loads
#pragma unroll
    for (int k = 0; k < KC; ++k)
      acc[k] += v.x * wr[k] + v.y * wr[KC + k] + v.z * wr[2 * KC + k] + v.w * wr[3 * KC + k];
  }
#pragma unroll
  for (int r = 0; r < 2; ++r) {
    float m = acc[0];
#pragma unroll
    for (int k = 1; k < KC; ++k) m = fmaxf(m, acc[k]);
    float sum = 0.f;
#pragma unroll
    for (int k = 0; k < KC; ++k) { acc[k] = expf(acc[k] - m); sum += acc[k]; }
    float inv = 1.f / sum;
#pragma unroll
    for (int k = 0; k < KC; ++k) acc[k] *= inv;
  }
  float4* so = (float4*)(s + (size_t)n * KC);
  so[0] = make_float4(acc[0], acc[1], acc[2], acc[3]);
  so[1] = make_float4(acc[4], acc[5], acc[6], acc[7]);
  so[2] = make_float4(acc[8], acc[9], acc[10], acc[11]);
  so[3] = make_float4(acc[12], acc[13], acc[14], acc[15]);
}

// -------------------- level-1: per-(graph,block) histogram --------------------
__global__ __launch_bounds__(256) void k_hist(const int* __restrict__ esrc,
    unsigned* __restrict__ blkhist) {
  __shared__ unsigned h[BG];
  const int t = threadIdx.x, b = blockIdx.x;
  if (t < BG) h[t] = 0u;
  __syncthreads();
  const int e0 = b * EH;
  for (int i = t; i < EH; i += 256) {
    unsigned g = (unsigned)esrc[e0 + i] / (unsigned)NPG;
    atomicAdd(&h[g], 1u);           // ds_add, no-return
  }
  __syncthreads();
  if (t < BG) blkhist[t * HB + b] = h[t];
}

// -------------------- level-1 scan A: per-graph scan over HB blocks --------------------
__global__ __launch_bounds__(1024) void k_scan_a(unsigned* __restrict__ blkhist,
    unsigned* __restrict__ gtot) {
  __shared__ unsigned wsum[16];
  const int t = threadIdx.x, g = blockIdx.x;
  const int lane = t & 63;
  unsigned v = blkhist[g * HB + t];
  unsigned inc = v;
#pragma unroll
  for (int o = 1; o < 64; o <<= 1) {
    unsigned nb = __shfl_up(inc, o, 64);
    if (lane >= o) inc += nb;
  }
  if (lane == 63) wsum[t >> 6] = inc;
  __syncthreads();
  if (t == 0) {
    unsigned run = 0;
#pragma unroll
    for (int i = 0; i < 16; ++i) { unsigned c = wsum[i]; wsum[i] = run; run += c; }
    gtot[g] = run;
  }
  __syncthreads();
  blkhist[g * HB + t] = inc - v + wsum[t >> 6];
}

// -------------------- level-1 scan B: graph bases --------------------
__global__ void k_scan_b(const unsigned* __restrict__ gtot, unsigned* __restrict__ gbase) {
  if (threadIdx.x == 0) {
    unsigned run = 0;
    for (int g = 0; g < BG; ++g) { gbase[g] = run; run += gtot[g]; }
    gbase[BG] = run;   // == NE
  }
}

// -------------------- level-1 scatter: sort by graph (owner-local runs) --------------------
__global__ __launch_bounds__(256) void k_scatter1(const float* __restrict__ ew,
    const int* __restrict__ esrc, const int* __restrict__ edst,
    const unsigned* __restrict__ blkhist, const unsigned* __restrict__ gbase,
    unsigned short* __restrict__ srcperm, unsigned* __restrict__ pay) {
  __shared__ unsigned h[BG];
  __shared__ unsigned off[BG];
  const int t = threadIdx.x, b = blockIdx.x;
  if (t < BG) { h[t] = 0u; off[t] = gbase[t] + blkhist[t * HB + b]; }
  __syncthreads();
  const int e0 = b * EH;
  for (int i = t; i < EH; i += 256) {
    int e = e0 + i;
    int s0 = esrc[e], d0 = edst[e];
    float w = ew[e];
    unsigned g = (unsigned)s0 / (unsigned)NPG;
    unsigned r = atomicAdd(&h[g], 1u);
    unsigned pos = off[g] + r;
    srcperm[pos] = (unsigned short)((unsigned)s0 - g * NPG);
    pay[pos] = (((unsigned)d0 - g * NPG) << 16) | f2bf(w);
  }
}

// -------------------- level-2: per-graph sort by src -> perm (in place) + row_ptr ----
__global__ __launch_bounds__(1024, 4) void k_sort2(unsigned short* srcperm,
    const unsigned* __restrict__ gbase, unsigned short* __restrict__ rowp) {
  __shared__ unsigned hist[NPG];
  __shared__ unsigned cur[NPG];
  const int t = threadIdx.x;
  const int g = blockIdx.x;
  const unsigned gb = gbase[g];
  const unsigned cnt = gbase[g + 1] - gb;   // ~51200, fits u16
  for (int i = t; i < NPG; i += 1024) hist[i] = 0u;
  __syncthreads();
  unsigned short sv[SMAX];                  // register snapshot of src keys
#pragma unroll
  for (int i = 0; i < SMAX; ++i) {
    unsigned e = (unsigned)t + (unsigned)(i * 1024);
    sv[i] = 0;
    if (e < cnt) {
      sv[i] = srcperm[gb + e];
      atomicAdd(&hist[sv[i]], 1u);
    }
  }
  __syncthreads();
  if (t < 64) {                             // wave-0 scan of 1600 counters
    unsigned loc[25];
    unsigned run = 0;
#pragma unroll
    for (int i = 0; i < 25; ++i) { loc[i] = run; run += hist[t * 25 + i]; }
    unsigned inc = run;
#pragma unroll
    for (int o = 1; o < 64; o <<= 1) {
      unsigned nb = __shfl_up(inc, o, 64);
      if (t >= o) inc += nb;
    }
    unsigned excl = inc - run;
#pragma unroll
    for (int i = 0; i < 25; ++i) cur[t * 25 + i] = excl + loc[i];
  }
  __syncthreads();
  for (int i = t; i < NPG; i += 1024) rowp[g * 1601 + i] = (unsigned short)cur[i];
  if (t == 0) rowp[g * 1601 + NPG] = (unsigned short)cnt;
  __syncthreads();
#pragma unroll
  for (int i = 0; i < SMAX; ++i) {          // scatter perm over own-graph region only
    unsigned e = (unsigned)t + (unsigned)(i * 1024);
    if (e < cnt) {
      unsigned r = atomicAdd(&cur[sv[i]], 1u);
      srcperm[gb + r] = (unsigned short)e;
    }
  }
}

// -------------------- adj = S^T A S via CSR register segment-sum; den folded ----------
__global__ __launch_bounds__(256, 6) void k_adj(const float* __restrict__ s,
    const unsigned short* __restrict__ perm, const unsigned* __restrict__ pay,
    const unsigned* __restrict__ gbase, const unsigned short* __restrict__ rowp,
    float* __restrict__ adj_raw, float* __restrict__ den) {
  __shared__ float red[16 * 256];
  __shared__ float scr[4];
  const int t = threadIdx.x;
  const int g = blockIdx.x & 63;            // all 32 blocks of graph g land on XCD g%8
  const int oct = blockIdx.x >> 6;          // 0..31
  const int l = t & 15;
  const int slice = oct * 16 + (t >> 4);    // 0..511
  const int sw = (t >> 4) & 3;
  const unsigned gb = gbase[g];
  const unsigned short* pg = perm + gb;
  const unsigned* pyg = pay + gb;
  const unsigned short* rp = rowp + g * 1601;
  const float* sG = s + (size_t)g * NPG * KC;
  float acc[16];
#pragma unroll
  for (int k = 0; k < 16; ++k) acc[k] = 0.f;
  float dacc = 0.f;
  for (int i = slice; i < NPG; i += 512) {
    unsigned e0 = rp[i], e1 = rp[i + 1];
    float m = 0.f;
    unsigned e = e0;
    for (; e + 2 <= e1; e += 2) {
      unsigned pi0 = pg[e], pi1 = pg[e + 1];
      unsigned pk0 = pyg[pi0], pk1 = pyg[pi1];
      float sv0 = sG[(pk0 >> 16) * KC + l];
      float sv1 = sG[(pk1 >> 16) * KC + l];
      float t0 = bf2f(pk0 & 0xFFFFu) * sv0;
      float t1 = bf2f(pk1 & 0xFFFFu) * sv1;
      m += t0 + t1;
      dacc = fmaf(t0, sv0, dacc);
      dacc = fmaf(t1, sv1, dacc);
    }
    if (e < e1) {
      unsigned pk0 = pyg[pg[e]];
      float sv0 = sG[(pk0 >> 16) * KC + l];
      float t0 = bf2f(pk0 & 0xFFFFu) * sv0;
      m += t0;
      dacc = fmaf(t0, sv0, dacc);
    }
    const float si = sG[i * KC + l];
#pragma unroll
    for (int k = 0; k < 16; ++k)
      acc[k] = fmaf(__shfl(si, sw * 16 + k, 64), m, acc[k]);
  }
  const int sb = t >> 4;
#pragma unroll
  for (int k = 0; k < 16; ++k) red[sb * 256 + k * 16 + l] = acc[k];
  __syncthreads();
  float sum = 0.f;
#pragma unroll
  for (int sl = 0; sl < 16; ++sl) sum += red[sl * 256 + t];
  glob_addf(adj_raw + g * 256 + t, sum);
#pragma unroll
  for (int o = 32; o > 0; o >>= 1) dacc += __shfl_down(dacc, o, 64);
  __syncthreads();
  if ((t & 63) == 0) scr[t >> 6] = dacc;
  __syncthreads();
  if (t == 0) glob_addf(den, scr[0] + scr[1] + scr[2] + scr[3]);
}

// -------------------- node pass: CC = S^T S, out_x = S^T X --------------------
__global__ __launch_bounds__(256, 8) void k_mid(const float* __restrict__ s,
    const float* __restrict__ x, float* __restrict__ cc_raw,
    float* __restrict__ outx_raw) {
  __shared__ float st[100 * KC];
  const int t = threadIdx.x;
  const int g = blockIdx.x >> 4, sub = blockIdx.x & 15;
  const int n0 = g * NPG + sub * 100;
  const int j = t & 127, h = t >> 7;
  const int kc = t >> 4, lc = t & 15;
  for (int u = t; u < 100 * KC; u += 256) st[u] = s[(size_t)n0 * KC + u];
  __syncthreads();
  float accX[8] = {0.f, 0.f, 0.f, 0.f, 0.f, 0.f, 0.f, 0.f};
  float accC = 0.f;
  for (int i = 0; i < 100; ++i) {
    const float xv = x[(size_t)(n0 + i) * FD + j];
    const float* si = st + i * KC;
#pragma unroll
    for (int kk = 0; kk < 8; ++kk) accX[kk] = fmaf(si[h * 8 + kk], xv, accX[kk]);
    accC = fmaf(si[kc], si[lc], accC);
  }
#pragma unroll
  for (int kk = 0; kk < 8; ++kk)
    glob_addf(outx_raw + g * 2048 + (h * 8 + kk) * 128 + j, accX[kk]);
  glob_addf(cc_raw + g * 256 + t, accC);
}

// -------------------- finalize: adj normalize, trace, ortho, SELU --------------------
__device__ __forceinline__ float bred(float v, float* scr) {
#pragma unroll
  for (int o = 32; o > 0; o >>= 1) v += __shfl_down(v, o, 64);
  __syncthreads();
  if ((threadIdx.x & 63) == 0) scr[threadIdx.x >> 6] = v;
  __syncthreads();
  return scr[0] + scr[1] + scr[2] + scr[3];
}

__global__ __launch_bounds__(256) void k_post(const float* __restrict__ adj_raw,
    const float* __restrict__ cc_raw, const float* __restrict__ outx_raw,
    float* __restrict__ out, float* __restrict__ ws_num, float* __restrict__ ws_ortho) {
  const int b = blockIdx.x, t = threadIdx.x;
  const int k = t >> 4, l = t & 15;
  __shared__ float m[16 * 17];
  __shared__ float dk[16];
  __shared__ float scr[4];
  const float raw = adj_raw[b * 256 + t];
  const float masked = (k == l) ? 0.f : raw;
  m[k * 17 + l] = masked;
  __syncthreads();
  if (t < 16) {
    float rs = 0.f;
#pragma unroll
    for (int ll = 0; ll < 16; ++ll) rs += m[t * 17 + ll];
    dk[t] = sqrtf(rs) + 1e-12f;
  }
  __syncthreads();
  out[131072 + b * 256 + t] = masked / (dk[k] * dk[l]);
  float tr = bred((k == l) ? raw : 0.f, scr);
  if (t == 0) glob_addf(ws_num, tr);
  const float c = cc_raw[b * 256 + t];
  float n2 = bred(c * c, scr);
  float diff = c / sqrtf(n2) - ((k == l) ? 0.25f : 0.f);
  float d2 = bred(diff * diff, scr);
  if (t == 0) glob_addf(ws_ortho, sqrtf(d2));
  for (int idx = b * 256 + t; idx < 131072; idx += 16384) {
    float xv = outx_raw[idx];
    out[idx] = xv > 0.f ? 1.0507009873554805f * xv
                        : 1.0507009873554805f * 1.6732632423543772f * expm1f(xv);
  }
}

__global__ void k_last(const float* __restrict__ scal, float* __restrict__ out) {
  out[147456] = -scal[1] / scal[0];      // -num/den
  out[147457] = scal[2] * (1.f / 64.f);  // mean ortho
}

// -------------------- launch --------------------
extern "C" void kernel_launch(void* const* d_in, const int* in_sizes, int n_in,
                              void* d_out, int out_size, void* d_ws, size_t ws_size,
                              hipStream_t stream) {
  const float* x  = (const float*)d_in[0];
  const float* W  = (const float*)d_in[1];
  const float* bb = (const float*)d_in[2];
  const float* ew = (const float*)d_in[3];
  const int* esrc = (const int*)d_in[4];
  const int* edst = (const int*)d_in[5];
  float* out = (float*)d_out;
  float* ws = (float*)d_ws;

  float* s_buf   = ws;                                    // 1,638,400 f
  float* adj_raw = s_buf + (size_t)NN * KC;               // 16,384 f
  float* cc_raw  = adj_raw + 16384;                       // 16,384 f
  float* outx    = cc_raw + 16384;                        // 131,072 f
  float* scal    = outx + 131072;                         // 8 f: [0]=den [1]=num [2]=ortho
  unsigned* blkhist = (unsigned*)(scal + 8);              // 64*1024 u
  unsigned* gtot    = blkhist + (size_t)BG * HB;          // 64 u
  unsigned* gbase   = gtot + BG;                          // 68 u (65 used)
  unsigned short* rowp = (unsigned short*)(gbase + 68);   // 64*1601 u16
  unsigned short* srcperm = rowp + 64 * 1601;             // NE u16 (src keys, then perm)
  unsigned* pay = (unsigned*)(srcperm + NE);              // NE u32 (dst<<16 | bf16 w)
  // total = 27,337,392 B = 27.3 MB  (< 33.69 MB proven available)

  hipMemsetAsync(adj_raw, 0, (size_t)(16384 + 16384 + 131072 + 8) * sizeof(float), stream);
  k_s<<<NN / 256, 256, 0, stream>>>(x, W, bb, s_buf);
  k_hist<<<HB, 256, 0, stream>>>(esrc, blkhist);
  k_scan_a<<<BG, 1024, 0, stream>>>(blkhist, gtot);
  k_scan_b<<<1, 64, 0, stream>>>(gtot, gbase);
  k_scatter1<<<HB, 256, 0, stream>>>(ew, esrc, edst, blkhist, gbase, srcperm, pay);
  k_sort2<<<BG, 1024, 0, stream>>>(srcperm, gbase, rowp);
  k_adj<<<BG * 32, 256, 0, stream>>>(s_buf, srcperm, pay, gbase, rowp, adj_raw, scal);
  k_mid<<<BG * 16, 256, 0, stream>>>(s_buf, x, cc_raw, outx);
  k_post<<<64, 256, 0, stream>>>(adj_raw, cc_raw, outx, out, scal + 1, scal + 2);
  k_last<<<1, 1, 0, stream>>>(scal, out);
}